// Round 11
// baseline (98.410 us; speedup 1.0000x reference)
//
#include <hip/hip_runtime.h>
#include <math.h>
#include <limits.h>

#define D 128
#define NSUBJ 16
#define MAXN 640        // bucket stride; groups ~512 +- 22 (~6 sigma safety)
#define MARGIN 0.8f
#define PRB 32          // rows per prep block
#define NPB 256         // prep blocks = 8192 / PRB
#define TI 16           // rows per MFMA row-tile
#define TIB 32          // i-rows per triplet block (2 MFMA row-tiles)
#define TJ 64           // j-cols per tile (4 waves x 16)
#define NSTRIPE 16      // stripes per subject
#define NBLK (NSUBJ * NSTRIPE)   // 256 blocks = 1/CU

typedef __attribute__((ext_vector_type(8))) short bf16x8;
typedef __attribute__((ext_vector_type(4))) float f32x4;

static __device__ __forceinline__ short f2bf(float f) {
    union { float f; unsigned u; } v; v.f = f;
    unsigned r = v.u + 0x7FFF + ((v.u >> 16) & 1);   // RNE
    return (short)(r >> 16);
}

// async global->LDS, 16B per lane: LDS dest = uniform base + lane*16 (HW),
// global src = fully per-lane address (pre-swizzled there if needed).
static __device__ __forceinline__ void gload_lds16(const void* g, void* l) {
    __builtin_amdgcn_global_load_lds(
        (const __attribute__((address_space(1))) void*)g,
        (__attribute__((address_space(3))) void*)l, 16, 0, 0);
}

// ---------------------------------------------------------------------------
// P1: per-block subject histogram (LDS atomics only). R8 version (plain
// stores — NT regressed in R10: nt streams toward HBM, slower consumer reads).
// ---------------------------------------------------------------------------
__global__ __launch_bounds__(64) void hist_kernel(const int* __restrict__ sbj,
                                                  int* __restrict__ hist) {
    __shared__ int s_cnt[NSUBJ];
    const int t = threadIdx.x, bid = blockIdx.x;
    if (t < NSUBJ) s_cnt[t] = 0;
    __syncthreads();
    if (t < PRB) atomicAdd(&s_cnt[sbj[bid * PRB + t]], 1);
    __syncthreads();
    if (t < NSUBJ) hist[bid * NSUBJ + t] = s_cnt[t];
}

// ---------------------------------------------------------------------------
// P2: scan fused into prep. R8 version (plain stores).
// ---------------------------------------------------------------------------
__global__ __launch_bounds__(256) void prep_kernel(
        const float* __restrict__ emb, const int* __restrict__ labels,
        const int* __restrict__ sbj, const int* __restrict__ hist,
        int* __restrict__ counts,
        int4* __restrict__ pmeta, short* __restrict__ ebf, int B) {
    __shared__ int s_cnt[NSUBJ], s_base[NSUBJ], s_slot[PRB];
    const int t = threadIdx.x, bid = blockIdx.x;
    if (t < NSUBJ) { s_cnt[t] = 0; s_base[t] = 0; }
    __syncthreads();
    {
        const int ss = t & 15, seg0 = (t >> 4) * 16;
        int part = 0;
        const int hi = min(bid, seg0 + 16);
        for (int b = seg0; b < hi; ++b) part += hist[b * NSUBJ + ss];
        if (part) atomicAdd(&s_base[ss], part);
    }
    int s = 0, mypos = 0;
    if (t < PRB) { s = sbj[bid * PRB + t]; mypos = atomicAdd(&s_cnt[s], 1); }
    __syncthreads();
    if (t < PRB) {
        int pos = s_base[s] + mypos;
        s_slot[t] = (pos < MAXN) ? (s * MAXN + pos) : -1;   // never fires at 6 sigma
    }
    if (bid == NPB - 1 && t < NSUBJ)
        counts[t] = s_base[t] + s_cnt[t];                   // totals for triplet
    __syncthreads();
#pragma unroll
    for (int it = 0; it < (PRB * 16) / 256; ++it) {         // 2 iters: 16 rows x 16 thr
        int lin = it * 256 + t;
        int row = lin >> 4, u = lin & 15;
        int i = bid * PRB + row;
        int slot = s_slot[row];
        const float4* rp = (const float4*)(emb + (size_t)i * D);
        float4 a0 = rp[u * 2], a1 = rp[u * 2 + 1];
        float ssq = 0.f;
        ssq = fmaf(a0.x, a0.x, ssq); ssq = fmaf(a0.y, a0.y, ssq);
        ssq = fmaf(a0.z, a0.z, ssq); ssq = fmaf(a0.w, a0.w, ssq);
        ssq = fmaf(a1.x, a1.x, ssq); ssq = fmaf(a1.y, a1.y, ssq);
        ssq = fmaf(a1.z, a1.z, ssq); ssq = fmaf(a1.w, a1.w, ssq);
#pragma unroll
        for (int off = 8; off > 0; off >>= 1) ssq += __shfl_down(ssq, off, 16);
        if (slot >= 0) {
            bf16x8 pk;
            pk[0] = f2bf(a0.x); pk[1] = f2bf(a0.y); pk[2] = f2bf(a0.z); pk[3] = f2bf(a0.w);
            pk[4] = f2bf(a1.x); pk[5] = f2bf(a1.y); pk[6] = f2bf(a1.z); pk[7] = f2bf(a1.w);
            *(bf16x8*)&ebf[(size_t)slot * D + u * 8] = pk;
            if (u == 0)
                pmeta[slot] = make_int4(labels[i], i, __float_as_int(ssq), 0);
        }
    }
}

// Stage one 64-row j-tile (16 KB, CONTIGUOUS in ebf) into LDS buffer BUF.
// LDS dest linear; global SOURCE carries the XOR swizzle (byte ^= (row&7)<<4,
// bits 4-6 only -> stays in-row); swizzled ds_read below undoes it.
#define STAGE(BUF, JT)                                                    \
    do {                                                                  \
        const char* ts_ = (const char*)ebf + ((size_t)(base + (JT) * TJ)) * 256; \
        _Pragma("unroll")                                                 \
        for (int ii_ = 0; ii_ < 4; ++ii_) {                               \
            int lin_ = ((w * 4 + ii_) * 64 + lane) * 16;                  \
            int row_ = lin_ >> 8;                                         \
            gload_lds16(ts_ + (lin_ ^ ((row_ & 7) << 4)),                 \
                        ldsB + (BUF) * (TJ * 256) + (w * 4 + ii_) * 1024);\
        }                                                                 \
    } while (0)

// Fused hardest-pos/neg select for one sub-tile from one acc quad.
#define SELECT(ACC, LI, GI, VP, IP, VN, IN, MI, ML, MS)                   \
    do {                                                                  \
        _Pragma("unroll")                                                 \
        for (int r = 0; r < 4; ++r) {                                     \
            float v = fmaf(-2.f, (ACC)[r], (MS));                         \
            if ((ML) == (LI)[r]) {                                        \
                if ((MI) != (GI)[r] && v > (VP)[r]) { (VP)[r] = v; (IP)[r] = (MI); } \
            } else if (v < (VN)[r]) { (VN)[r] = v; (IN)[r] = (MI); }      \
        }                                                                 \
    } while (0)

// triplet: 2 i-tiles (32 rows) per block, 256 blocks = 1/CU. Each staged
// B-tile now feeds 8 MFMA (was 4): staging traffic + per-block fixed costs
// halve per output, and the doubled compute phase widens the vmcnt slack
// (R5 lesson: fewer/fatter blocks; R8 lever: LDS staging). Same LDS-staged
// dbuf with counted vmcnt(4) + raw s_barrier. Selection semantics identical.
__global__ __launch_bounds__(256, 1) void triplet_kernel(
        const short* __restrict__ ebf, const int4* __restrict__ pmeta,
        const int* __restrict__ counts,
        float* __restrict__ bsum, int* __restrict__ bcnt) {
    const int bid = blockIdx.x, t = threadIdx.x;
    const int s = bid & 15;              // subject -> XCD s%8 (all stripes pinned)
    const int stripe = bid >> 4;         // 0..15
    const int base = s * MAXN;
    const int n = min(counts[s], MAXN);
    const int lane = t & 63, w = t >> 6, c = lane & 15, q = lane >> 4;

    __shared__ char ldsB[2 * TJ * 256];  // 32 KB: double-buffered B-tile (swizzled)
    __shared__ char ldsM[MAXN * 16];     // 10 KB: whole panel meta (linear)
    __shared__ float svP[TIB][4]; __shared__ int siP[TIB][4];
    __shared__ float svN[TIB][4]; __shared__ int siN[TIB][4];

    const int ntiles = (n + TJ - 1) / TJ;

    // stage entire panel meta once (oldest in vmcnt queue; drained with tile 0)
    for (int r = w; r < ntiles; r += 4)
        gload_lds16((const char*)(pmeta + base + r * 64) + lane * 16,
                    ldsM + r * 1024);

    float blockSum = 0.f; int blockCnt = 0;

    for (int i0 = stripe * TIB; i0 < n; i0 += NSTRIPE * TIB) {
        const int nrows = min(TIB, n - i0);
        const int nr0 = min(nrows, TI);
        const int nr1 = nrows - nr0;                 // 0..16

        // A fragments for both sub-tiles (prologue-only scattered loads)
        bf16x8 afr0[4], afr1[4];
        {
            const short* ap0 = ebf + (size_t)(base + i0 + min(c, nr0 - 1)) * D;
            const int r1 = (nr1 > 0) ? (i0 + TI + min(c, nr1 - 1)) : i0;
            const short* ap1 = ebf + (size_t)(base + r1) * D;
#pragma unroll
            for (int st = 0; st < 4; ++st) {
                afr0[st] = *(const bf16x8*)&ap0[st * 32 + q * 8];
                afr1[st] = *(const bf16x8*)&ap1[st * 32 + q * 8];
            }
        }
        int li0[4], gI0[4], li1[4], gI1[4];
#pragma unroll
        for (int r = 0; r < 4; ++r) {
            int row = q * 4 + r;
            if (row < nr0) { int4 m = pmeta[base + i0 + row];      li0[r] = m.x; gI0[r] = m.y; }
            else           { li0[r] = INT_MIN; gI0[r] = -1; }
            if (row < nr1) { int4 m = pmeta[base + i0 + TI + row]; li1[r] = m.x; gI1[r] = m.y; }
            else           { li1[r] = INT_MIN; gI1[r] = -1; }
        }

        float vP0[4], vN0[4], vP1[4], vN1[4];
        int   iP0[4], iN0[4], iP1[4], iN1[4];
#pragma unroll
        for (int r = 0; r < 4; ++r) {
            vP0[r] = -INFINITY; iP0[r] = -1; vN0[r] = INFINITY; iN0[r] = -1;
            vP1[r] = -INFINITY; iP1[r] = -1; vN1[r] = INFINITY; iN1[r] = -1;
        }

        // ---- prologue: stage tiles 0,1 ----
        STAGE(0, 0);
        if (1 < ntiles) STAGE(1, 1);
        int cur = 0;

        for (int jt = 0; jt < ntiles; ++jt) {
            if (jt + 1 < ntiles) asm volatile("s_waitcnt vmcnt(4)" ::: "memory");
            else                 asm volatile("s_waitcnt vmcnt(0)" ::: "memory");
            __builtin_amdgcn_sched_barrier(0);
            __builtin_amdgcn_s_barrier();          // all waves' stages landed
            __builtin_amdgcn_sched_barrier(0);

            {   // consume buf cur: swizzled ds_read + 8 MFMA + 2x fused select
                const char* bb = ldsB + cur * (TJ * 256);
                const int lr = w * 16 + c, swz = (lr & 7) << 4;
                bf16x8 f0 = *(const bf16x8*)(bb + lr * 256 + ((  0 + q * 16) ^ swz));
                bf16x8 f1 = *(const bf16x8*)(bb + lr * 256 + (( 64 + q * 16) ^ swz));
                bf16x8 f2 = *(const bf16x8*)(bb + lr * 256 + ((128 + q * 16) ^ swz));
                bf16x8 f3 = *(const bf16x8*)(bb + lr * 256 + ((192 + q * 16) ^ swz));
                const int jl = jt * TJ + lr;
                int4 m = *(const int4*)(ldsM + jl * 16);
                const int MI = (jl < n) ? m.y : -1;
                const int ML = m.x; const float MS = __int_as_float(m.z);

                f32x4 acc0 = {0.f, 0.f, 0.f, 0.f};
                acc0 = __builtin_amdgcn_mfma_f32_16x16x32_bf16(afr0[0], f0, acc0, 0, 0, 0);
                acc0 = __builtin_amdgcn_mfma_f32_16x16x32_bf16(afr0[1], f1, acc0, 0, 0, 0);
                acc0 = __builtin_amdgcn_mfma_f32_16x16x32_bf16(afr0[2], f2, acc0, 0, 0, 0);
                acc0 = __builtin_amdgcn_mfma_f32_16x16x32_bf16(afr0[3], f3, acc0, 0, 0, 0);
                f32x4 acc1 = {0.f, 0.f, 0.f, 0.f};
                acc1 = __builtin_amdgcn_mfma_f32_16x16x32_bf16(afr1[0], f0, acc1, 0, 0, 0);
                acc1 = __builtin_amdgcn_mfma_f32_16x16x32_bf16(afr1[1], f1, acc1, 0, 0, 0);
                acc1 = __builtin_amdgcn_mfma_f32_16x16x32_bf16(afr1[2], f2, acc1, 0, 0, 0);
                acc1 = __builtin_amdgcn_mfma_f32_16x16x32_bf16(afr1[3], f3, acc1, 0, 0, 0);
                if (MI >= 0) {
                    SELECT(acc0, li0, gI0, vP0, iP0, vN0, iN0, MI, ML, MS);
                    SELECT(acc1, li1, gI1, vP1, iP1, vN1, iN1, MI, ML, MS);
                }
            }

            __builtin_amdgcn_s_barrier();          // all waves done reading cur
            __builtin_amdgcn_sched_barrier(0);
            if (jt + 2 < ntiles) STAGE(cur, jt + 2);  // refill freed buffer
            cur ^= 1;
        }

        // reduce across the 16 col-lanes (tie-break: smallest original index)
#pragma unroll
        for (int off = 8; off > 0; off >>= 1) {
#pragma unroll
            for (int r = 0; r < 4; ++r) {
                float ov; int oi;
                ov = __shfl_down(vP0[r], off, 16); oi = __shfl_down(iP0[r], off, 16);
                if (ov > vP0[r] || (ov == vP0[r] && (unsigned)oi < (unsigned)iP0[r])) { vP0[r] = ov; iP0[r] = oi; }
                ov = __shfl_down(vN0[r], off, 16); oi = __shfl_down(iN0[r], off, 16);
                if (ov < vN0[r] || (ov == vN0[r] && (unsigned)oi < (unsigned)iN0[r])) { vN0[r] = ov; iN0[r] = oi; }
                ov = __shfl_down(vP1[r], off, 16); oi = __shfl_down(iP1[r], off, 16);
                if (ov > vP1[r] || (ov == vP1[r] && (unsigned)oi < (unsigned)iP1[r])) { vP1[r] = ov; iP1[r] = oi; }
                ov = __shfl_down(vN1[r], off, 16); oi = __shfl_down(iN1[r], off, 16);
                if (ov < vN1[r] || (ov == vN1[r] && (unsigned)oi < (unsigned)iN1[r])) { vN1[r] = ov; iN1[r] = oi; }
            }
        }
        if (c == 0) {
#pragma unroll
            for (int r = 0; r < 4; ++r) {
                int row = q * 4 + r;
                svP[row][w] = vP0[r]; siP[row][w] = iP0[r];
                svN[row][w] = vN0[r]; siN[row][w] = iN0[r];
                svP[TI + row][w] = vP1[r]; siP[TI + row][w] = iP1[r];
                svN[TI + row][w] = vN1[r]; siN[TI + row][w] = iN1[r];
            }
        }
        __syncthreads();

        // per-row combine + loss directly from d2 (32 rows, lanes 0..31 wave 0)
        if (t < TIB) {
            float bp = svP[t][0]; int ip = siP[t][0];
            float bn = svN[t][0]; int in_ = siN[t][0];
#pragma unroll
            for (int ww = 1; ww < 4; ++ww) {
                float o = svP[t][ww]; int oi = siP[t][ww];
                if (o > bp || (o == bp && (unsigned)oi < (unsigned)ip)) { bp = o; ip = oi; }
                float on = svN[t][ww]; int oj = siN[t][ww];
                if (on < bn || (on == bn && (unsigned)oj < (unsigned)in_)) { bn = on; in_ = oj; }
            }
            bool valid = (t < nrows) && (ip >= 0) && (in_ >= 0);
            float sqi = __int_as_float(
                ((const int4*)(ldsM + (i0 + min(t, nrows - 1)) * 16))->z);
            float per = 0.f;
            if (valid) {
                float dap = sqrtf(fmaxf(bp + sqi, 0.f));
                float dan = sqrtf(fmaxf(bn + sqi, 0.f));
                per = fmaxf(dap - dan + MARGIN, 0.f);
            }
            int vc = valid ? 1 : 0;
#pragma unroll
            for (int off = 16; off > 0; off >>= 1) {   // lanes 0..31 of wave 0
                per += __shfl_down(per, off, 32);
                vc  += __shfl_down(vc,  off, 32);
            }
            if (t == 0) { blockSum += per; blockCnt += vc; }
        }
        if (i0 + NSTRIPE * TIB < n) __syncthreads();   // barrier only if another stripe
    }

    // ---- epilogue: plain per-block partial store (no atomics, no fence) ----
    if (t == 0) { bsum[bid] = blockSum; bcnt[bid] = blockCnt; }
}

// finalize: tree-sum the 256 partials and write the mean.
__global__ __launch_bounds__(256) void finalize_kernel(
        const float* __restrict__ bsum, const int* __restrict__ bcnt,
        float* __restrict__ out) {
    __shared__ float ssum[4]; __shared__ int scnt[4];
    const int t = threadIdx.x;
    float s = 0.f; int c = 0;
#pragma unroll
    for (int i = t; i < NBLK; i += 256) { s += bsum[i]; c += bcnt[i]; }
#pragma unroll
    for (int off = 32; off > 0; off >>= 1) {
        s += __shfl_down(s, off, 64);
        c += __shfl_down(c, off, 64);
    }
    if ((t & 63) == 0) { ssum[t >> 6] = s; scnt[t >> 6] = c; }
    __syncthreads();
    if (t == 0) {
        float S = ssum[0] + ssum[1] + ssum[2] + ssum[3];
        int   C = scnt[0] + scnt[1] + scnt[2] + scnt[3];
        out[0] = (C > 0) ? (S / (float)C) : 0.0f;
    }
}

extern "C" void kernel_launch(void* const* d_in, const int* in_sizes, int n_in,
                              void* d_out, int out_size, void* d_ws, size_t ws_size,
                              hipStream_t stream) {
    const float* emb    = (const float*)d_in[0];
    const int*   labels = (const int*)d_in[1];
    const int*   sbj    = (const int*)d_in[2];
    float*       out    = (float*)d_out;
    int B = in_sizes[1];   // 8192

    // Workspace:
    //   [0,64)      int counts[16]
    //   [256,1280)  float bsum[NBLK]
    //   [1280,2304) int bcnt[NBLK]
    //   [align, +NPB*NSUBJ*4)        int hist[NPB][NSUBJ] (16 KB)
    //   [align256, +NSUBJ*MAXN*16)   int4 pmeta (160 KB)
    //   [align256, +NSUBJ*MAXN*D*2)  short ebf (~2.62 MB)
    char*  ws        = (char*)d_ws;
    int*   counts    = (int*)ws;
    float* bsum      = (float*)(ws + 256);
    int*   bcnt      = (int*)(ws + 256 + NBLK * sizeof(float));
    int*   hist      = (int*)(ws + 256 + 2 * NBLK * sizeof(int));
    size_t pmeta_off = (256 + 2 * (size_t)NBLK * sizeof(int)
                        + (size_t)NPB * NSUBJ * sizeof(int) + 255) & ~(size_t)255;
    int4*  pmeta     = (int4*)(ws + pmeta_off);
    size_t ebf_off   = (pmeta_off + (size_t)NSUBJ * MAXN * sizeof(int4) + 255) & ~(size_t)255;
    short* ebf       = (short*)(ws + ebf_off);

    hist_kernel<<<B / PRB, 64, 0, stream>>>(sbj, hist);
    prep_kernel<<<B / PRB, 256, 0, stream>>>(emb, labels, sbj, hist, counts,
                                             pmeta, ebf, B);
    triplet_kernel<<<NBLK, 256, 0, stream>>>(ebf, pmeta, counts, bsum, bcnt);
    finalize_kernel<<<1, 256, 0, stream>>>(bsum, bcnt, out);
}

// Round 12
// 87.052 us; speedup vs baseline: 1.1305x; 1.1305x over previous
//
#include <hip/hip_runtime.h>
#include <math.h>
#include <limits.h>

#define D 128
#define NSUBJ 16
#define MAXN 640        // bucket stride; groups ~512 +- 22 (~6 sigma safety)
#define MARGIN 0.8f
#define PRB 32          // rows per prep block
#define NPB 256         // prep blocks = 8192 / PRB
#define TI 16           // i-rows per triplet block (one MFMA row-tile)
#define TJ 64           // j-cols per tile (4 waves x 16)
#define NSTRIPE 32      // stripes per subject
#define NBLK (NSUBJ * NSTRIPE)   // 512 blocks = 2/CU (R5/R11 bracket: optimum)

typedef __attribute__((ext_vector_type(8))) short bf16x8;
typedef __attribute__((ext_vector_type(4))) float f32x4;

static __device__ __forceinline__ short f2bf(float f) {
    union { float f; unsigned u; } v; v.f = f;
    unsigned r = v.u + 0x7FFF + ((v.u >> 16) & 1);   // RNE
    return (short)(r >> 16);
}

// async global->LDS, 16B per lane: LDS dest = uniform base + lane*16 (HW),
// global src = fully per-lane address (pre-swizzled there if needed).
static __device__ __forceinline__ void gload_lds16(const void* g, void* l) {
    __builtin_amdgcn_global_load_lds(
        (const __attribute__((address_space(1))) void*)g,
        (__attribute__((address_space(3))) void*)l, 16, 0, 0);
}

// ---------------------------------------------------------------------------
// P1: per-block subject histogram (LDS atomics only). R8 version.
// ---------------------------------------------------------------------------
__global__ __launch_bounds__(64) void hist_kernel(const int* __restrict__ sbj,
                                                  int* __restrict__ hist) {
    __shared__ int s_cnt[NSUBJ];
    const int t = threadIdx.x, bid = blockIdx.x;
    if (t < NSUBJ) s_cnt[t] = 0;
    __syncthreads();
    if (t < PRB) atomicAdd(&s_cnt[sbj[bid * PRB + t]], 1);
    __syncthreads();
    if (t < NSUBJ) hist[bid * NSUBJ + t] = s_cnt[t];
}

// ---------------------------------------------------------------------------
// P2: scan fused into prep. R8 version (plain stores — NT regressed in R10).
// ---------------------------------------------------------------------------
__global__ __launch_bounds__(256) void prep_kernel(
        const float* __restrict__ emb, const int* __restrict__ labels,
        const int* __restrict__ sbj, const int* __restrict__ hist,
        int* __restrict__ counts,
        int4* __restrict__ pmeta, short* __restrict__ ebf, int B) {
    __shared__ int s_cnt[NSUBJ], s_base[NSUBJ], s_slot[PRB];
    const int t = threadIdx.x, bid = blockIdx.x;
    if (t < NSUBJ) { s_cnt[t] = 0; s_base[t] = 0; }
    __syncthreads();
    {
        const int ss = t & 15, seg0 = (t >> 4) * 16;
        int part = 0;
        const int hi = min(bid, seg0 + 16);
        for (int b = seg0; b < hi; ++b) part += hist[b * NSUBJ + ss];
        if (part) atomicAdd(&s_base[ss], part);
    }
    int s = 0, mypos = 0;
    if (t < PRB) { s = sbj[bid * PRB + t]; mypos = atomicAdd(&s_cnt[s], 1); }
    __syncthreads();
    if (t < PRB) {
        int pos = s_base[s] + mypos;
        s_slot[t] = (pos < MAXN) ? (s * MAXN + pos) : -1;   // never fires at 6 sigma
    }
    if (bid == NPB - 1 && t < NSUBJ)
        counts[t] = s_base[t] + s_cnt[t];                   // totals for triplet
    __syncthreads();
#pragma unroll
    for (int it = 0; it < (PRB * 16) / 256; ++it) {         // 2 iters: 16 rows x 16 thr
        int lin = it * 256 + t;
        int row = lin >> 4, u = lin & 15;
        int i = bid * PRB + row;
        int slot = s_slot[row];
        const float4* rp = (const float4*)(emb + (size_t)i * D);
        float4 a0 = rp[u * 2], a1 = rp[u * 2 + 1];
        float ssq = 0.f;
        ssq = fmaf(a0.x, a0.x, ssq); ssq = fmaf(a0.y, a0.y, ssq);
        ssq = fmaf(a0.z, a0.z, ssq); ssq = fmaf(a0.w, a0.w, ssq);
        ssq = fmaf(a1.x, a1.x, ssq); ssq = fmaf(a1.y, a1.y, ssq);
        ssq = fmaf(a1.z, a1.z, ssq); ssq = fmaf(a1.w, a1.w, ssq);
#pragma unroll
        for (int off = 8; off > 0; off >>= 1) ssq += __shfl_down(ssq, off, 16);
        if (slot >= 0) {
            bf16x8 pk;
            pk[0] = f2bf(a0.x); pk[1] = f2bf(a0.y); pk[2] = f2bf(a0.z); pk[3] = f2bf(a0.w);
            pk[4] = f2bf(a1.x); pk[5] = f2bf(a1.y); pk[6] = f2bf(a1.z); pk[7] = f2bf(a1.w);
            *(bf16x8*)&ebf[(size_t)slot * D + u * 8] = pk;
            if (u == 0)
                pmeta[slot] = make_int4(labels[i], i, __float_as_int(ssq), 0);
        }
    }
}

// Stage one 64-row j-tile (16 KB, CONTIGUOUS in ebf) into LDS buffer BUF.
// LDS dest linear; global SOURCE carries the XOR swizzle (byte ^= (row&7)<<4,
// bits 4-6 only -> stays in-row); swizzled ds_read below undoes it.
#define STAGE(BUF, JT)                                                    \
    do {                                                                  \
        const char* ts_ = (const char*)ebf + ((size_t)(base + (JT) * TJ)) * 256; \
        _Pragma("unroll")                                                 \
        for (int ii_ = 0; ii_ < 4; ++ii_) {                               \
            int lin_ = ((w * 4 + ii_) * 64 + lane) * 16;                  \
            int row_ = lin_ >> 8;                                         \
            gload_lds16(ts_ + (lin_ ^ ((row_ & 7) << 4)),                 \
                        ldsB + (BUF) * (TJ * 256) + (w * 4 + ii_) * 1024);\
        }                                                                 \
    } while (0)

// triplet: R8 structure, upgraded to a 4-deep LDS ring with ONE barrier per
// j-tile. Stage target for tile jt+3 is the buffer consumed at jt-1 — every
// wave finished reading it before the top-of-jt barrier (program order:
// consume(jt-1) precedes that barrier), so the trailing barrier is deleted.
// Steady-state vmcnt(8): 3 tiles (12 loads/wave) in flight, wait for oldest.
// Sync count halves (8 vs 16 barriers); staging slack ~3x. 2 blocks/CU kept
// (77 KB LDS x2 = 154 <= 160 KB) — R5/R11 showed cross-block TLP is the
// latency-hiding mechanism. Arithmetic bit-identical to R8.
__global__ __launch_bounds__(256, 2) void triplet_kernel(
        const short* __restrict__ ebf, const int4* __restrict__ pmeta,
        const int* __restrict__ counts,
        float* __restrict__ bsum, int* __restrict__ bcnt) {
    const int bid = blockIdx.x, t = threadIdx.x;
    const int s = bid & 15;              // subject -> XCD s%8 (blocks 16k+s pinned)
    const int stripe = bid >> 4;         // 0..31
    const int base = s * MAXN;
    const int n = min(counts[s], MAXN);
    const int lane = t & 63, w = t >> 6, c = lane & 15, q = lane >> 4;

    __shared__ char ldsB[4 * TJ * 256];  // 64 KB: 4-deep B-tile ring (swizzled)
    __shared__ char ldsM[MAXN * 16];     // 10 KB: whole panel meta (linear)
    __shared__ float svP[TI][4]; __shared__ int siP[TI][4];
    __shared__ float svN[TI][4]; __shared__ int siN[TI][4];

    const int ntiles = (n + TJ - 1) / TJ;

    // stage entire panel meta once (oldest in vmcnt queue; drained by the
    // first counted wait together with tile 0)
    for (int r = w; r < ntiles; r += 4)
        gload_lds16((const char*)(pmeta + base + r * 64) + lane * 16,
                    ldsM + r * 1024);

    float blockSum = 0.f; int blockCnt = 0;

    for (int i0 = stripe * TI; i0 < n; i0 += NSTRIPE * TI) {
        const int nrows = min(TI, n - i0);

        // A fragments (row = i0 + c) + i-row meta, from global (prologue-only)
        bf16x8 afr[4];
        {
            const short* ap = ebf + (size_t)(base + i0 + min(c, nrows - 1)) * D;
#pragma unroll
            for (int st = 0; st < 4; ++st)
                afr[st] = *(const bf16x8*)&ap[st * 32 + q * 8];
        }
        int li[4], gI[4];
#pragma unroll
        for (int r = 0; r < 4; ++r) {
            int row = q * 4 + r;
            if (row < nrows) { int4 m = pmeta[base + i0 + row]; li[r] = m.x; gI[r] = m.y; }
            else             { li[r] = INT_MIN; gI[r] = -1; }
        }

        float vP[4], vN[4]; int iP[4], iN[4];
#pragma unroll
        for (int r = 0; r < 4; ++r) {
            vP[r] = -INFINITY; iP[r] = -1;
            vN[r] =  INFINITY; iN[r] = -1;
        }

        // ---- prologue: stage tiles 0,1,2 into ring slots 0,1,2 ----
        STAGE(0, 0);
        if (1 < ntiles) STAGE(1, 1);
        if (2 < ntiles) STAGE(2, 2);

        for (int jt = 0; jt < ntiles; ++jt) {
            // counted wait: oldest in-flight tile (jt) must land; leave the
            // younger 2 tiles (8 loads/wave) in flight
            if (jt + 2 < ntiles)      asm volatile("s_waitcnt vmcnt(8)" ::: "memory");
            else if (jt + 1 < ntiles) asm volatile("s_waitcnt vmcnt(4)" ::: "memory");
            else                      asm volatile("s_waitcnt vmcnt(0)" ::: "memory");
            __builtin_amdgcn_sched_barrier(0);
            __builtin_amdgcn_s_barrier();          // all waves' tile-jt stages landed
            __builtin_amdgcn_sched_barrier(0);

            {   // consume ring slot jt&3: swizzled ds_read + MFMA + fused select
                const char* bb = ldsB + (jt & 3) * (TJ * 256);
                const int lr = w * 16 + c, swz = (lr & 7) << 4;
                bf16x8 f0 = *(const bf16x8*)(bb + lr * 256 + ((  0 + q * 16) ^ swz));
                bf16x8 f1 = *(const bf16x8*)(bb + lr * 256 + (( 64 + q * 16) ^ swz));
                bf16x8 f2 = *(const bf16x8*)(bb + lr * 256 + ((128 + q * 16) ^ swz));
                bf16x8 f3 = *(const bf16x8*)(bb + lr * 256 + ((192 + q * 16) ^ swz));
                const int jl = jt * TJ + lr;
                int4 m = *(const int4*)(ldsM + jl * 16);
                const int MI = (jl < n) ? m.y : -1;
                const int ML = m.x; const float MS = __int_as_float(m.z);

                f32x4 acc = {0.f, 0.f, 0.f, 0.f};
                acc = __builtin_amdgcn_mfma_f32_16x16x32_bf16(afr[0], f0, acc, 0, 0, 0);
                acc = __builtin_amdgcn_mfma_f32_16x16x32_bf16(afr[1], f1, acc, 0, 0, 0);
                acc = __builtin_amdgcn_mfma_f32_16x16x32_bf16(afr[2], f2, acc, 0, 0, 0);
                acc = __builtin_amdgcn_mfma_f32_16x16x32_bf16(afr[3], f3, acc, 0, 0, 0);
                if (MI >= 0) {
#pragma unroll
                    for (int r = 0; r < 4; ++r) {
                        float v = fmaf(-2.f, acc[r], MS);
                        if (ML == li[r]) {
                            if (MI != gI[r] && v > vP[r]) { vP[r] = v; iP[r] = MI; }
                        } else if (v < vN[r]) { vN[r] = v; iN[r] = MI; }
                    }
                }
            }

            // NO trailing barrier: stage tile jt+3 into slot (jt+3)&3 — that
            // slot held tile jt-1, which every wave finished reading before
            // the top-of-jt barrier (consume precedes it in program order).
            __builtin_amdgcn_sched_barrier(0);
            if (jt + 3 < ntiles) STAGE((jt + 3) & 3, jt + 3);
        }

        // reduce across the 16 col-lanes (tie-break: smallest original index)
#pragma unroll
        for (int off = 8; off > 0; off >>= 1) {
#pragma unroll
            for (int r = 0; r < 4; ++r) {
                float ov = __shfl_down(vP[r], off, 16);
                int   oi = __shfl_down(iP[r], off, 16);
                if (ov > vP[r] || (ov == vP[r] && (unsigned)oi < (unsigned)iP[r])) {
                    vP[r] = ov; iP[r] = oi;
                }
                float on = __shfl_down(vN[r], off, 16);
                int   oj = __shfl_down(iN[r], off, 16);
                if (on < vN[r] || (on == vN[r] && (unsigned)oj < (unsigned)iN[r])) {
                    vN[r] = on; iN[r] = oj;
                }
            }
        }
        if (c == 0) {
#pragma unroll
            for (int r = 0; r < 4; ++r) {
                int row = q * 4 + r;
                svP[row][w] = vP[r]; siP[row][w] = iP[r];
                svN[row][w] = vN[r]; siN[row][w] = iN[r];
            }
        }
        __syncthreads();

        // per-row combine + loss directly from d2:
        // d2 = (sq_j - 2 dot) + sq_i ; dap/dan = sqrt(max(d2,0))
        if (t < TI) {
            float bp = svP[t][0]; int ip = siP[t][0];
            float bn = svN[t][0]; int in_ = siN[t][0];
#pragma unroll
            for (int ww = 1; ww < 4; ++ww) {
                float o = svP[t][ww]; int oi = siP[t][ww];
                if (o > bp || (o == bp && (unsigned)oi < (unsigned)ip)) { bp = o; ip = oi; }
                float on = svN[t][ww]; int oj = siN[t][ww];
                if (on < bn || (on == bn && (unsigned)oj < (unsigned)in_)) { bn = on; in_ = oj; }
            }
            bool valid = (t < nrows) && (ip >= 0) && (in_ >= 0);
            float sqi = __int_as_float(
                ((const int4*)(ldsM + (i0 + min(t, nrows - 1)) * 16))->z);
            float per = 0.f;
            if (valid) {
                float dap = sqrtf(fmaxf(bp + sqi, 0.f));
                float dan = sqrtf(fmaxf(bn + sqi, 0.f));
                per = fmaxf(dap - dan + MARGIN, 0.f);
            }
            int vc = valid ? 1 : 0;
#pragma unroll
            for (int off = 8; off > 0; off >>= 1) {   // t<16 = lanes 0..15 of wave 0
                per += __shfl_down(per, off, 16);
                vc  += __shfl_down(vc,  off, 16);
            }
            if (t == 0) { blockSum += per; blockCnt += vc; }
        }
        if (i0 + NSTRIPE * TI < n) __syncthreads();   // barrier only if another stripe
    }

    // ---- epilogue: plain per-block partial store (no atomics, no fence) ----
    if (t == 0) { bsum[bid] = blockSum; bcnt[bid] = blockCnt; }
}

// finalize: tree-sum the 512 partials (4 KB) and write the mean. R4 version.
__global__ __launch_bounds__(256) void finalize_kernel(
        const float* __restrict__ bsum, const int* __restrict__ bcnt,
        float* __restrict__ out) {
    __shared__ float ssum[4]; __shared__ int scnt[4];
    const int t = threadIdx.x;
    float s = 0.f; int c = 0;
#pragma unroll
    for (int i = t; i < NBLK; i += 256) { s += bsum[i]; c += bcnt[i]; }
#pragma unroll
    for (int off = 32; off > 0; off >>= 1) {
        s += __shfl_down(s, off, 64);
        c += __shfl_down(c, off, 64);
    }
    if ((t & 63) == 0) { ssum[t >> 6] = s; scnt[t >> 6] = c; }
    __syncthreads();
    if (t == 0) {
        float S = ssum[0] + ssum[1] + ssum[2] + ssum[3];
        int   C = scnt[0] + scnt[1] + scnt[2] + scnt[3];
        out[0] = (C > 0) ? (S / (float)C) : 0.0f;
    }
}

extern "C" void kernel_launch(void* const* d_in, const int* in_sizes, int n_in,
                              void* d_out, int out_size, void* d_ws, size_t ws_size,
                              hipStream_t stream) {
    const float* emb    = (const float*)d_in[0];
    const int*   labels = (const int*)d_in[1];
    const int*   sbj    = (const int*)d_in[2];
    float*       out    = (float*)d_out;
    int B = in_sizes[1];   // 8192

    // Workspace:
    //   [0,64)      int counts[16]
    //   [256,2304)  float bsum[NBLK]
    //   [2304,4352) int bcnt[NBLK]
    //   [4352, +NPB*NSUBJ*4)         int hist[NPB][NSUBJ] (16 KB)
    //   [align256, +NSUBJ*MAXN*16)   int4 pmeta (160 KB)
    //   [align256, +NSUBJ*MAXN*D*2)  short ebf (~2.62 MB)
    char*  ws        = (char*)d_ws;
    int*   counts    = (int*)ws;
    float* bsum      = (float*)(ws + 256);
    int*   bcnt      = (int*)(ws + 256 + NBLK * sizeof(float));
    int*   hist      = (int*)(ws + 256 + 2 * NBLK * sizeof(int));
    size_t pmeta_off = (256 + 2 * (size_t)NBLK * sizeof(int)
                        + (size_t)NPB * NSUBJ * sizeof(int) + 255) & ~(size_t)255;
    int4*  pmeta     = (int4*)(ws + pmeta_off);
    size_t ebf_off   = (pmeta_off + (size_t)NSUBJ * MAXN * sizeof(int4) + 255) & ~(size_t)255;
    short* ebf       = (short*)(ws + ebf_off);

    hist_kernel<<<B / PRB, 64, 0, stream>>>(sbj, hist);
    prep_kernel<<<B / PRB, 256, 0, stream>>>(emb, labels, sbj, hist, counts,
                                             pmeta, ebf, B);
    triplet_kernel<<<NBLK, 256, 0, stream>>>(ebf, pmeta, counts, bsum, bcnt);
    finalize_kernel<<<1, 256, 0, stream>>>(bsum, bcnt, out);
}

// Round 13
// 86.053 us; speedup vs baseline: 1.1436x; 1.0116x over previous
//
#include <hip/hip_runtime.h>
#include <math.h>
#include <limits.h>

#define D 128
#define NSUBJ 16
#define MAXN 640        // bucket stride; groups ~512 +- 22 (~6 sigma safety)
#define MARGIN 0.8f
#define PRB 32          // rows per prep block
#define NPB 256         // prep blocks = 8192 / PRB
#define TI 16           // i-rows per triplet block (one MFMA row-tile)
#define TJ 128          // j-cols per tile (8 waves x 16)
#define NSTRIPE 32      // stripes per subject
#define NBLK (NSUBJ * NSTRIPE)   // 512 blocks = 2/CU (R5/R11 bracket: optimum)

typedef __attribute__((ext_vector_type(8))) short bf16x8;
typedef __attribute__((ext_vector_type(4))) float f32x4;

static __device__ __forceinline__ short f2bf(float f) {
    union { float f; unsigned u; } v; v.f = f;
    unsigned r = v.u + 0x7FFF + ((v.u >> 16) & 1);   // RNE
    return (short)(r >> 16);
}

// async global->LDS, 16B per lane: LDS dest = uniform base + lane*16 (HW),
// global src = fully per-lane address (pre-swizzled there if needed).
static __device__ __forceinline__ void gload_lds16(const void* g, void* l) {
    __builtin_amdgcn_global_load_lds(
        (const __attribute__((address_space(1))) void*)g,
        (__attribute__((address_space(3))) void*)l, 16, 0, 0);
}

// ---------------------------------------------------------------------------
// P1: per-block subject histogram (LDS atomics only). R8 version.
// ---------------------------------------------------------------------------
__global__ __launch_bounds__(64) void hist_kernel(const int* __restrict__ sbj,
                                                  int* __restrict__ hist) {
    __shared__ int s_cnt[NSUBJ];
    const int t = threadIdx.x, bid = blockIdx.x;
    if (t < NSUBJ) s_cnt[t] = 0;
    __syncthreads();
    if (t < PRB) atomicAdd(&s_cnt[sbj[bid * PRB + t]], 1);
    __syncthreads();
    if (t < NSUBJ) hist[bid * NSUBJ + t] = s_cnt[t];
}

// ---------------------------------------------------------------------------
// P2: scan fused into prep. R8 version (plain stores — NT regressed in R10).
// ---------------------------------------------------------------------------
__global__ __launch_bounds__(256) void prep_kernel(
        const float* __restrict__ emb, const int* __restrict__ labels,
        const int* __restrict__ sbj, const int* __restrict__ hist,
        int* __restrict__ counts,
        int4* __restrict__ pmeta, short* __restrict__ ebf, int B) {
    __shared__ int s_cnt[NSUBJ], s_base[NSUBJ], s_slot[PRB];
    const int t = threadIdx.x, bid = blockIdx.x;
    if (t < NSUBJ) { s_cnt[t] = 0; s_base[t] = 0; }
    __syncthreads();
    {
        const int ss = t & 15, seg0 = (t >> 4) * 16;
        int part = 0;
        const int hi = min(bid, seg0 + 16);
        for (int b = seg0; b < hi; ++b) part += hist[b * NSUBJ + ss];
        if (part) atomicAdd(&s_base[ss], part);
    }
    int s = 0, mypos = 0;
    if (t < PRB) { s = sbj[bid * PRB + t]; mypos = atomicAdd(&s_cnt[s], 1); }
    __syncthreads();
    if (t < PRB) {
        int pos = s_base[s] + mypos;
        s_slot[t] = (pos < MAXN) ? (s * MAXN + pos) : -1;   // never fires at 6 sigma
    }
    if (bid == NPB - 1 && t < NSUBJ)
        counts[t] = s_base[t] + s_cnt[t];                   // totals for triplet
    __syncthreads();
#pragma unroll
    for (int it = 0; it < (PRB * 16) / 256; ++it) {         // 2 iters: 16 rows x 16 thr
        int lin = it * 256 + t;
        int row = lin >> 4, u = lin & 15;
        int i = bid * PRB + row;
        int slot = s_slot[row];
        const float4* rp = (const float4*)(emb + (size_t)i * D);
        float4 a0 = rp[u * 2], a1 = rp[u * 2 + 1];
        float ssq = 0.f;
        ssq = fmaf(a0.x, a0.x, ssq); ssq = fmaf(a0.y, a0.y, ssq);
        ssq = fmaf(a0.z, a0.z, ssq); ssq = fmaf(a0.w, a0.w, ssq);
        ssq = fmaf(a1.x, a1.x, ssq); ssq = fmaf(a1.y, a1.y, ssq);
        ssq = fmaf(a1.z, a1.z, ssq); ssq = fmaf(a1.w, a1.w, ssq);
#pragma unroll
        for (int off = 8; off > 0; off >>= 1) ssq += __shfl_down(ssq, off, 16);
        if (slot >= 0) {
            bf16x8 pk;
            pk[0] = f2bf(a0.x); pk[1] = f2bf(a0.y); pk[2] = f2bf(a0.z); pk[3] = f2bf(a0.w);
            pk[4] = f2bf(a1.x); pk[5] = f2bf(a1.y); pk[6] = f2bf(a1.z); pk[7] = f2bf(a1.w);
            *(bf16x8*)&ebf[(size_t)slot * D + u * 8] = pk;
            if (u == 0)
                pmeta[slot] = make_int4(labels[i], i, __float_as_int(ssq), 0);
        }
    }
}

// Stage one 128-row j-tile (32 KB, CONTIGUOUS in ebf) into LDS buffer BUF.
// 4 gload_lds per wave x 8 waves = 32 KB. LDS dest linear; global SOURCE
// carries the XOR swizzle (byte ^= (row&7)<<4, bits 4-6 -> stays in-row);
// the swizzled ds_read below undoes it (both-sides involution).
#define STAGE(BUF, JT)                                                    \
    do {                                                                  \
        const char* ts_ = (const char*)ebf + ((size_t)(base + (JT) * TJ)) * 256; \
        _Pragma("unroll")                                                 \
        for (int ii_ = 0; ii_ < 4; ++ii_) {                               \
            int lin_ = ((w * 4 + ii_) * 64 + lane) * 16;                  \
            int row_ = lin_ >> 8;                                         \
            gload_lds16(ts_ + (lin_ ^ ((row_ & 7) << 4)),                 \
                        ldsB + (BUF) * (TJ * 256) + (w * 4 + ii_) * 1024);\
        }                                                                 \
    } while (0)

// triplet: 8-wave blocks (512 thr), TJ=128. Doubles wave-TLP to 16/CU at the
// proven 2 blocks/CU (74.5 KB LDS x2 = 149 <= 160), halves barrier count
// (4 tiles x 2 vs 8 x 2) and tile count. R8's dbuf + counted vmcnt schedule.
// Meta staging is wave-nonuniform at ntiles~4, so it is DRAINED once before
// the j-loop (vmcnt(0)+barrier) — all later counted waits are then uniform
// pure-tile counts. Arithmetic/selection/tie-breaks bit-identical to R8.
__global__ __launch_bounds__(512, 4) void triplet_kernel(
        const short* __restrict__ ebf, const int4* __restrict__ pmeta,
        const int* __restrict__ counts,
        float* __restrict__ bsum, int* __restrict__ bcnt) {
    const int bid = blockIdx.x, t = threadIdx.x;
    const int s = bid & 15;              // subject -> XCD s%8 (blocks 16k+s pinned)
    const int stripe = bid >> 4;         // 0..31
    const int base = s * MAXN;
    const int n = min(counts[s], MAXN);
    const int lane = t & 63, w = t >> 6, c = lane & 15, q = lane >> 4;

    __shared__ char ldsB[2 * TJ * 256];  // 64 KB: double-buffered 128-row tile
    __shared__ char ldsM[MAXN * 16];     // 10 KB: whole panel meta (linear)
    __shared__ float svP[TI][8]; __shared__ int siP[TI][8];
    __shared__ float svN[TI][8]; __shared__ int siN[TI][8];

    const int ntiles = (n + TJ - 1) / TJ;        // ~4-5
    const int mchunks = (n + 63) >> 6;           // 64-row meta chunks (~8-10)

    // ---- stage panel meta, then DRAIN (nonuniform per wave at 8 waves) ----
    for (int r = w; r < mchunks; r += 8)
        gload_lds16((const char*)(pmeta + base + r * 64) + lane * 16,
                    ldsM + r * 1024);
    asm volatile("s_waitcnt vmcnt(0)" ::: "memory");
    __builtin_amdgcn_s_barrier();

    float blockSum = 0.f; int blockCnt = 0;

    for (int i0 = stripe * TI; i0 < n; i0 += NSTRIPE * TI) {
        const int nrows = min(TI, n - i0);

        // A fragments (row = i0 + c) + i-row meta (from LDS meta, now resident)
        bf16x8 afr[4];
        {
            const short* ap = ebf + (size_t)(base + i0 + min(c, nrows - 1)) * D;
#pragma unroll
            for (int st = 0; st < 4; ++st)
                afr[st] = *(const bf16x8*)&ap[st * 32 + q * 8];
        }
        int li[4], gI[4];
#pragma unroll
        for (int r = 0; r < 4; ++r) {
            int row = q * 4 + r;
            if (row < nrows) {
                int4 m = *(const int4*)(ldsM + (i0 + row) * 16);
                li[r] = m.x; gI[r] = m.y;
            } else { li[r] = INT_MIN; gI[r] = -1; }
        }

        float vP[4], vN[4]; int iP[4], iN[4];
#pragma unroll
        for (int r = 0; r < 4; ++r) {
            vP[r] = -INFINITY; iP[r] = -1;
            vN[r] =  INFINITY; iN[r] = -1;
        }

        // ---- prologue: stage tiles 0,1 ----
        STAGE(0, 0);
        if (1 < ntiles) STAGE(1, 1);
        int cur = 0;

        for (int jt = 0; jt < ntiles; ++jt) {
            // wait own 4 stages for tile jt (leave next tile's 4 in flight)
            if (jt + 1 < ntiles) asm volatile("s_waitcnt vmcnt(4)" ::: "memory");
            else                 asm volatile("s_waitcnt vmcnt(0)" ::: "memory");
            __builtin_amdgcn_sched_barrier(0);
            __builtin_amdgcn_s_barrier();          // all waves' stages landed
            __builtin_amdgcn_sched_barrier(0);

            {   // consume buf cur: swizzled ds_read + MFMA + fused select
                const char* bb = ldsB + cur * (TJ * 256);
                const int lr = w * 16 + c, swz = (lr & 7) << 4;
                bf16x8 f0 = *(const bf16x8*)(bb + lr * 256 + ((  0 + q * 16) ^ swz));
                bf16x8 f1 = *(const bf16x8*)(bb + lr * 256 + (( 64 + q * 16) ^ swz));
                bf16x8 f2 = *(const bf16x8*)(bb + lr * 256 + ((128 + q * 16) ^ swz));
                bf16x8 f3 = *(const bf16x8*)(bb + lr * 256 + ((192 + q * 16) ^ swz));
                const int jl = jt * TJ + lr;
                int4 m = *(const int4*)(ldsM + min(jl, n - 1) * 16);
                const int MI = (jl < n) ? m.y : -1;
                const int ML = m.x; const float MS = __int_as_float(m.z);

                f32x4 acc = {0.f, 0.f, 0.f, 0.f};
                acc = __builtin_amdgcn_mfma_f32_16x16x32_bf16(afr[0], f0, acc, 0, 0, 0);
                acc = __builtin_amdgcn_mfma_f32_16x16x32_bf16(afr[1], f1, acc, 0, 0, 0);
                acc = __builtin_amdgcn_mfma_f32_16x16x32_bf16(afr[2], f2, acc, 0, 0, 0);
                acc = __builtin_amdgcn_mfma_f32_16x16x32_bf16(afr[3], f3, acc, 0, 0, 0);
                if (MI >= 0) {
#pragma unroll
                    for (int r = 0; r < 4; ++r) {
                        float v = fmaf(-2.f, acc[r], MS);
                        if (ML == li[r]) {
                            if (MI != gI[r] && v > vP[r]) { vP[r] = v; iP[r] = MI; }
                        } else if (v < vN[r]) { vN[r] = v; iN[r] = MI; }
                    }
                }
            }

            __builtin_amdgcn_s_barrier();          // all waves done reading cur
            __builtin_amdgcn_sched_barrier(0);
            if (jt + 2 < ntiles) STAGE(cur, jt + 2);  // refill freed buffer
            cur ^= 1;
        }

        // reduce across the 16 col-lanes (tie-break: smallest original index)
#pragma unroll
        for (int off = 8; off > 0; off >>= 1) {
#pragma unroll
            for (int r = 0; r < 4; ++r) {
                float ov = __shfl_down(vP[r], off, 16);
                int   oi = __shfl_down(iP[r], off, 16);
                if (ov > vP[r] || (ov == vP[r] && (unsigned)oi < (unsigned)iP[r])) {
                    vP[r] = ov; iP[r] = oi;
                }
                float on = __shfl_down(vN[r], off, 16);
                int   oj = __shfl_down(iN[r], off, 16);
                if (on < vN[r] || (on == vN[r] && (unsigned)oj < (unsigned)iN[r])) {
                    vN[r] = on; iN[r] = oj;
                }
            }
        }
        if (c == 0) {
#pragma unroll
            for (int r = 0; r < 4; ++r) {
                int row = q * 4 + r;
                svP[row][w] = vP[r]; siP[row][w] = iP[r];
                svN[row][w] = vN[r]; siN[row][w] = iN[r];
            }
        }
        __syncthreads();

        // per-row combine (8 waves) + loss directly from d2:
        // d2 = (sq_j - 2 dot) + sq_i ; dap/dan = sqrt(max(d2,0))
        if (t < TI) {
            float bp = svP[t][0]; int ip = siP[t][0];
            float bn = svN[t][0]; int in_ = siN[t][0];
#pragma unroll
            for (int ww = 1; ww < 8; ++ww) {
                float o = svP[t][ww]; int oi = siP[t][ww];
                if (o > bp || (o == bp && (unsigned)oi < (unsigned)ip)) { bp = o; ip = oi; }
                float on = svN[t][ww]; int oj = siN[t][ww];
                if (on < bn || (on == bn && (unsigned)oj < (unsigned)in_)) { bn = on; in_ = oj; }
            }
            bool valid = (t < nrows) && (ip >= 0) && (in_ >= 0);
            float sqi = __int_as_float(
                ((const int4*)(ldsM + (i0 + min(t, nrows - 1)) * 16))->z);
            float per = 0.f;
            if (valid) {
                float dap = sqrtf(fmaxf(bp + sqi, 0.f));
                float dan = sqrtf(fmaxf(bn + sqi, 0.f));
                per = fmaxf(dap - dan + MARGIN, 0.f);
            }
            int vc = valid ? 1 : 0;
#pragma unroll
            for (int off = 8; off > 0; off >>= 1) {   // t<16 = lanes 0..15 of wave 0
                per += __shfl_down(per, off, 16);
                vc  += __shfl_down(vc,  off, 16);
            }
            if (t == 0) { blockSum += per; blockCnt += vc; }
        }
        if (i0 + NSTRIPE * TI < n) __syncthreads();   // barrier only if another stripe
    }

    // ---- epilogue: plain per-block partial store (no atomics, no fence) ----
    if (t == 0) { bsum[bid] = blockSum; bcnt[bid] = blockCnt; }
}

// finalize: tree-sum the 512 partials (4 KB) and write the mean. R4 version.
__global__ __launch_bounds__(256) void finalize_kernel(
        const float* __restrict__ bsum, const int* __restrict__ bcnt,
        float* __restrict__ out) {
    __shared__ float ssum[4]; __shared__ int scnt[4];
    const int t = threadIdx.x;
    float s = 0.f; int c = 0;
#pragma unroll
    for (int i = t; i < NBLK; i += 256) { s += bsum[i]; c += bcnt[i]; }
#pragma unroll
    for (int off = 32; off > 0; off >>= 1) {
        s += __shfl_down(s, off, 64);
        c += __shfl_down(c, off, 64);
    }
    if ((t & 63) == 0) { ssum[t >> 6] = s; scnt[t >> 6] = c; }
    __syncthreads();
    if (t == 0) {
        float S = ssum[0] + ssum[1] + ssum[2] + ssum[3];
        int   C = scnt[0] + scnt[1] + scnt[2] + scnt[3];
        out[0] = (C > 0) ? (S / (float)C) : 0.0f;
    }
}

extern "C" void kernel_launch(void* const* d_in, const int* in_sizes, int n_in,
                              void* d_out, int out_size, void* d_ws, size_t ws_size,
                              hipStream_t stream) {
    const float* emb    = (const float*)d_in[0];
    const int*   labels = (const int*)d_in[1];
    const int*   sbj    = (const int*)d_in[2];
    float*       out    = (float*)d_out;
    int B = in_sizes[1];   // 8192

    // Workspace:
    //   [0,64)      int counts[16]
    //   [256,2304)  float bsum[NBLK]
    //   [2304,4352) int bcnt[NBLK]
    //   [4352, +NPB*NSUBJ*4)         int hist[NPB][NSUBJ] (16 KB)
    //   [align256, +NSUBJ*MAXN*16)   int4 pmeta (160 KB)
    //   [align256, +NSUBJ*MAXN*D*2)  short ebf (~2.62 MB)
    char*  ws        = (char*)d_ws;
    int*   counts    = (int*)ws;
    float* bsum      = (float*)(ws + 256);
    int*   bcnt      = (int*)(ws + 256 + NBLK * sizeof(float));
    int*   hist      = (int*)(ws + 256 + 2 * NBLK * sizeof(int));
    size_t pmeta_off = (256 + 2 * (size_t)NBLK * sizeof(int)
                        + (size_t)NPB * NSUBJ * sizeof(int) + 255) & ~(size_t)255;
    int4*  pmeta     = (int4*)(ws + pmeta_off);
    size_t ebf_off   = (pmeta_off + (size_t)NSUBJ * MAXN * sizeof(int4) + 255) & ~(size_t)255;
    short* ebf       = (short*)(ws + ebf_off);

    hist_kernel<<<B / PRB, 64, 0, stream>>>(sbj, hist);
    prep_kernel<<<B / PRB, 256, 0, stream>>>(emb, labels, sbj, hist, counts,
                                             pmeta, ebf, B);
    triplet_kernel<<<NBLK, 512, 0, stream>>>(ebf, pmeta, counts, bsum, bcnt);
    finalize_kernel<<<1, 256, 0, stream>>>(bsum, bcnt, out);
}